// Round 2
// 316.203 us; speedup vs baseline: 1.6890x; 1.6890x over previous
//
#include <hip/hip_runtime.h>
#include <math.h>

// Causal linear attention, chunkwise. Shapes fixed by the reference:
// [N=4, L=4096, H=16, D=64], M=64, CHUNK=128, G=32.
static constexpr int Nn = 4, Ll = 4096, Hh = 16, Dd = 64, Mm = 64, Cc = 128, Gg = 32;
static constexpr int ROWS = Hh * Dd;  // 1024 floats: l-stride in [N,L,H,D]
#define EPS_ 1e-6f

typedef __bf16 bf16x8 __attribute__((ext_vector_type(8)));
typedef unsigned short us8 __attribute__((ext_vector_type(8)));
typedef float f32x4 __attribute__((ext_vector_type(4)));

__device__ __forceinline__ float phi(float x) {
    // elu(x)+1 = x+1 (x>0) else exp(x)
    return x > 0.0f ? x + 1.0f : __expf(x);
}

// bf16 round-to-nearest-even via bit trick
__device__ __forceinline__ unsigned short f2bf(float x) {
    unsigned u = __float_as_uint(x);
    return (unsigned short)((u + 0x7fffu + ((u >> 16) & 1u)) >> 16);
}
__device__ __forceinline__ float bf2f(unsigned short h) {
    return __uint_as_float(((unsigned)h) << 16);
}

// D = A*B + C, A,B bf16 16x32 / 32x16, C/D f32 16x16.
// A: row = lane&15, k = (lane>>4)*8+e ; B: col = lane&15, k = (lane>>4)*8+e
// C/D: col = lane&15, row = (lane>>4)*4 + reg   (HW-verified layout)
#define MFMA16(A, B, C)                                                      \
    __builtin_amdgcn_mfma_f32_16x16x32_bf16(__builtin_bit_cast(bf16x8, (A)), \
                                            __builtin_bit_cast(bf16x8, (B)), \
                                            (C), 0, 0, 0)

// 16B-granule XOR swizzles (consistent on write and read; kill stride bank
// conflicts on the b128 fragment reads).
__device__ __forceinline__ int KIDX(int j, int d) {   // K [128 j][64 d]
    return j * 64 + ((((d >> 3) ^ j) & 7) << 3) + (d & 7);
}
__device__ __forceinline__ int VTIDX(int m, int j) {  // T-layout [64 rows][128 cols]
    return m * 128 + ((((j >> 3) ^ m) & 15) << 3) + (j & 7);
}
__device__ __forceinline__ int KVIDX(int m, int d) {  // KVt [64 m][64 d]
    return m * 64 + ((((d >> 3) ^ m) & 7) << 3) + (d & 7);
}
__device__ __forceinline__ int SIDX(int r, int j) {   // S scratch [16 r][32 j]
    return r * 32 + ((((j >> 3) ^ (r >> 1)) & 3) << 3) + (j & 7);
}

__device__ __forceinline__ void load8(const float* p, float* xs) {
    float4 a = *(const float4*)p, b = *(const float4*)(p + 4);
    xs[0] = a.x; xs[1] = a.y; xs[2] = a.z; xs[3] = a.w;
    xs[4] = b.x; xs[5] = b.y; xs[6] = b.z; xs[7] = b.w;
}

// ---------------------------------------------------------------------------
// Kernel 1: per-chunk TRANSPOSED KV state via MFMA.
//   kvT[m][d] = sum_c v[c][m] * phi(k[c][d])   (= (V^T . phi(K)) [m][d])
//   ksum[d]   = sum_c phi(k[c][d])
// One block per (n,g,h), 4 waves; wave w owns m-tile [w*16, w*16+16).
// Both operands staged transposed in LDS as bf16 hi/lo (paired b32 writes).
// ---------------------------------------------------------------------------
__global__ __launch_bounds__(256) void kv_state_kernel(
    const float* __restrict__ keys, const float* __restrict__ values,
    float* __restrict__ kvbuf, float* __restrict__ ksumbuf)
{
    __shared__ alignas(16) unsigned short KthS[64 * 128];  // kT [d][c] hi
    __shared__ alignas(16) unsigned short KtlS[64 * 128];  // kT [d][c] lo
    __shared__ alignas(16) unsigned short VthS[64 * 128];  // vT [m][c] hi
    __shared__ alignas(16) unsigned short VtlS[64 * 128];  // vT [m][c] lo

    const int b = blockIdx.x;
    const int h = b % Hh;
    const int g = (b / Hh) % Gg;
    const int n = b / (Hh * Gg);
    const int tid = threadIdx.x;

    const size_t inbase = ((size_t)(n * Ll + g * Cc) * Hh + h) * Dd;

    // stage both transposes: row-pairs -> packed u32 (hi|hi<<16) writes
    for (int i = tid; i < 1024; i += 256) {
        const int jp = i >> 4, d4 = (i & 15) * 4;
        const int c0 = jp * 2;
        const float4 ka = *(const float4*)(keys   + inbase + (size_t)c0 * ROWS + d4);
        const float4 kb = *(const float4*)(keys   + inbase + (size_t)(c0 + 1) * ROWS + d4);
        const float4 va = *(const float4*)(values + inbase + (size_t)c0 * ROWS + d4);
        const float4 vb = *(const float4*)(values + inbase + (size_t)(c0 + 1) * ROWS + d4);
        const float kaa[4] = {ka.x, ka.y, ka.z, ka.w};
        const float kbb[4] = {kb.x, kb.y, kb.z, kb.w};
        const float vaa[4] = {va.x, va.y, va.z, va.w};
        const float vbb[4] = {vb.x, vb.y, vb.z, vb.w};
        #pragma unroll
        for (int e = 0; e < 4; ++e) {
            const int idx = VTIDX(d4 + e, c0);  // c0 even -> u32-aligned, same granule
            const float pa = phi(kaa[e]), pb = phi(kbb[e]);
            const unsigned ha = f2bf(pa), hb = f2bf(pb);
            *(unsigned*)(KthS + idx) = ha | (hb << 16);
            const unsigned la = f2bf(pa - bf2f((unsigned short)ha));
            const unsigned lb = f2bf(pb - bf2f((unsigned short)hb));
            *(unsigned*)(KtlS + idx) = la | (lb << 16);
            const unsigned hva = f2bf(vaa[e]), hvb = f2bf(vbb[e]);
            *(unsigned*)(VthS + idx) = hva | (hvb << 16);
            const unsigned lva = f2bf(vaa[e] - bf2f((unsigned short)hva));
            const unsigned lvb = f2bf(vbb[e] - bf2f((unsigned short)hvb));
            *(unsigned*)(VtlS + idx) = lva | (lvb << 16);
        }
    }
    __syncthreads();

    const int w = tid >> 6, l = tid & 63;
    const int lr = l & 15, lg = l >> 4;

    // A = vT fragments for this wave's m-tile
    us8 ah[4], al[4];
    #pragma unroll
    for (int cs = 0; cs < 4; ++cs) {
        ah[cs] = *(const us8*)(VthS + VTIDX(w * 16 + lr, cs * 32 + lg * 8));
        al[cs] = *(const us8*)(VtlS + VTIDX(w * 16 + lr, cs * 32 + lg * 8));
    }

    float* kvout = kvbuf + ((size_t)((n * Gg + g) * Hh + h)) * (Dd * Mm);
    #pragma unroll
    for (int dt = 0; dt < 4; ++dt) {
        f32x4 acc = {0.f, 0.f, 0.f, 0.f};
        #pragma unroll
        for (int cs = 0; cs < 4; ++cs) {
            us8 bh = *(const us8*)(KthS + VTIDX(dt * 16 + lr, cs * 32 + lg * 8));
            us8 bl = *(const us8*)(KtlS + VTIDX(dt * 16 + lr, cs * 32 + lg * 8));
            acc = MFMA16(ah[cs], bh, acc);
            acc = MFMA16(ah[cs], bl, acc);
            acc = MFMA16(al[cs], bh, acc);
        }
        // C layout: row (m within tile) = lg*4+r, col (d within tile) = lr
        #pragma unroll
        for (int r = 0; r < 4; ++r)
            kvout[(size_t)(w * 16 + lg * 4 + r) * 64 + dt * 16 + lr] = acc[r];
    }

    if (tid < 64) {
        float s = 0.f;
        #pragma unroll
        for (int gb = 0; gb < 16; ++gb) {
            us8 hh = *(const us8*)(KthS + VTIDX(tid, gb * 8));
            us8 ll = *(const us8*)(KtlS + VTIDX(tid, gb * 8));
            #pragma unroll
            for (int e = 0; e < 8; ++e) s += bf2f(hh[e]) + bf2f(ll[e]);
        }
        ksumbuf[((size_t)((n * Gg + g) * Hh + h)) * 64 + tid] = s;
    }
}

// ---------------------------------------------------------------------------
// Kernel 2: in-place EXCLUSIVE prefix over g for kvbuf and ksumbuf.
// (layout-agnostic over the 4096 dm entries per state)
// ---------------------------------------------------------------------------
__global__ __launch_bounds__(256) void prefix_kernel(
    float* __restrict__ kvbuf, float* __restrict__ ksumbuf)
{
    const int t = blockIdx.x * 256 + threadIdx.x;
    const int NKV = Nn * Hh * Dd * Mm;  // 262144
    if (t < NKV) {
        const int nh = t >> 12, dm = t & 4095;
        const int n = nh >> 4, h = nh & 15;
        float run = 0.f;
        for (int g = 0; g < Gg; ++g) {
            const size_t idx = ((size_t)((n * Gg + g) * Hh + h)) * 4096 + dm;
            const float v = kvbuf[idx];
            kvbuf[idx] = run;
            run += v;
        }
    } else {
        const int t2 = t - NKV;
        if (t2 < Nn * Hh * Dd) {
            const int nh = t2 >> 6, d = t2 & 63;
            const int n = nh >> 4, h = nh & 15;
            float run = 0.f;
            for (int g = 0; g < Gg; ++g) {
                const size_t idx = ((size_t)((n * Gg + g) * Hh + h)) * 64 + d;
                const float v = ksumbuf[idx];
                ksumbuf[idx] = run;
                run += v;
            }
        }
    }
}

// ---------------------------------------------------------------------------
// Kernel 3: MFMA out kernel. One block per (n,g,h) chunk, 4 waves.
// Wave w owns 16-row tiles T = w and 7-w (balanced causal triangle).
// All matmuls (QK^T, S.V, Q.KVprev) use bf16 hi/lo split MFMA (3-term):
//   AB ~= Ah.Bh + Ah.Bl + Al.Bh   -> fp32-grade accuracy, matrix-pipe FLOPs.
// ---------------------------------------------------------------------------
__global__ __launch_bounds__(256) void out_kernel(
    const float* __restrict__ queries,
    const float* __restrict__ keys,
    const float* __restrict__ values,
    const float* __restrict__ kvbuf,
    const float* __restrict__ ksumbuf,
    float* __restrict__ out)
{
    __shared__ alignas(16) unsigned short KhS[128 * 64];   // 16 KB phi(k) hi
    __shared__ alignas(16) unsigned short KlS[128 * 64];   // 16 KB phi(k) lo
    __shared__ alignas(16) unsigned short VthS[64 * 128];  // 16 KB V^T hi
    __shared__ alignas(16) unsigned short VtlS[64 * 128];  // 16 KB V^T lo
    __shared__ alignas(16) unsigned short KVhS[64 * 64];   //  8 KB KVprev^T hi
    __shared__ alignas(16) unsigned short KVlS[64 * 64];   //  8 KB KVprev^T lo
    __shared__ alignas(16) unsigned short SshS[4 * 2 * 512]; // 8 KB per-wave dbuf S hi
    __shared__ alignas(16) unsigned short SslS[4 * 2 * 512]; // 8 KB per-wave dbuf S lo
    __shared__ float kpreS[64];

    const int b = blockIdx.x;
    const int h = b & 15, g = (b >> 4) & 31, n = b >> 9;
    const int tid = threadIdx.x;

    const size_t chunkbase = ((size_t)(n * Ll + g * Cc) * Hh + h) * Dd;
    const size_t stateoff  = (size_t)((n * Gg + g) * Hh + h);

    // ---- stage kpre (exclusive prefix of column-sums of phi(k)) ----
    if (tid < 16)
        *(float4*)(kpreS + tid * 4) =
            *(const float4*)(ksumbuf + stateoff * 64 + tid * 4);

    // ---- stage phi(k) hi/lo, granule-swizzled (contiguous us8 writes) ----
    for (int t = tid; t < 1024; t += 256) {
        const int j = t >> 3, gb = t & 7;
        float xs[8];
        load8(keys + chunkbase + (size_t)j * ROWS + gb * 8, xs);
        us8 hh, ll;
        #pragma unroll
        for (int e = 0; e < 8; ++e) {
            const float p = phi(xs[e]);
            const unsigned short hb = f2bf(p);
            hh[e] = hb; ll[e] = f2bf(p - bf2f(hb));
        }
        const int base = KIDX(j, gb * 8);
        *(us8*)(KhS + base) = hh;
        *(us8*)(KlS + base) = ll;
    }
    // ---- stage V transposed hi/lo (row pairs -> packed b32 writes) ----
    for (int t = tid; t < 1024; t += 256) {
        const int jp = t >> 4, m4 = (t & 15) * 4;
        const int j0 = jp * 2;
        const float4 va = *(const float4*)(values + chunkbase + (size_t)j0 * ROWS + m4);
        const float4 vb = *(const float4*)(values + chunkbase + (size_t)(j0 + 1) * ROWS + m4);
        const float vaa[4] = {va.x, va.y, va.z, va.w};
        const float vbb[4] = {vb.x, vb.y, vb.z, vb.w};
        #pragma unroll
        for (int e = 0; e < 4; ++e) {
            const int idx = VTIDX(m4 + e, j0);  // j0 even -> aligned, same granule
            const unsigned hva = f2bf(vaa[e]), hvb = f2bf(vbb[e]);
            *(unsigned*)(VthS + idx) = hva | (hvb << 16);
            const unsigned lva = f2bf(vaa[e] - bf2f((unsigned short)hva));
            const unsigned lvb = f2bf(vbb[e] - bf2f((unsigned short)hvb));
            *(unsigned*)(VtlS + idx) = lva | (lvb << 16);
        }
    }
    // ---- stage KVprev^T hi/lo ----
    {
        const float* kvp = kvbuf + stateoff * (size_t)(Dd * Mm);  // kvT [m][d]
        for (int t = tid; t < 512; t += 256) {
            const int m = t >> 3, gb = t & 7;
            float xs[8];
            load8(kvp + m * 64 + gb * 8, xs);
            us8 hh, ll;
            #pragma unroll
            for (int e = 0; e < 8; ++e) {
                const unsigned short hb = f2bf(xs[e]);
                hh[e] = hb; ll[e] = f2bf(xs[e] - bf2f(hb));
            }
            const int base = KVIDX(m, gb * 8);
            *(us8*)(KVhS + base) = hh;
            *(us8*)(KVlS + base) = ll;
        }
    }
    __syncthreads();

    const int w = tid >> 6, l = tid & 63;
    const int lr = l & 15, lg = l >> 4;

    for (int tt = 0; tt < 2; ++tt) {
        const int T = tt ? (7 - w) : w;  // balanced pairing: {w, 7-w}

        // ---- Q fragments straight from global (phi + split) and u = Q.kpre ----
        us8 qh[2], ql[2];
        float u = 0.f;
        #pragma unroll
        for (int ks = 0; ks < 2; ++ks) {
            float xs[8];
            load8(queries + chunkbase + (size_t)(T * 16 + lr) * ROWS + ks * 32 + lg * 8, xs);
            us8 hh, ll;
            #pragma unroll
            for (int e = 0; e < 8; ++e) {
                const float p = phi(xs[e]);
                u += p * kpreS[ks * 32 + lg * 8 + e];
                const unsigned short hb = f2bf(p);
                hh[e] = hb; ll[e] = f2bf(p - bf2f(hb));
            }
            qh[ks] = hh; ql[ks] = ll;
        }
        // reduce u over the 4 d-groups; afterwards lane i<16 holds u for row T*16+i
        u += __shfl_xor(u, 16, 64);
        u += __shfl_xor(u, 32, 64);

        // ---- inter: accO = Q . KVprev ----
        f32x4 accO[4];
        #pragma unroll
        for (int mt = 0; mt < 4; ++mt) {
            f32x4 acc = {0.f, 0.f, 0.f, 0.f};
            #pragma unroll
            for (int ks = 0; ks < 2; ++ks) {
                us8 bh = *(const us8*)(KVhS + KVIDX(mt * 16 + lr, ks * 32 + lg * 8));
                us8 bl = *(const us8*)(KVlS + KVIDX(mt * 16 + lr, ks * 32 + lg * 8));
                acc = MFMA16(qh[ks], bh, acc);
                acc = MFMA16(qh[ks], bl, acc);
                acc = MFMA16(ql[ks], bh, acc);
            }
            accO[mt] = acc;
        }

        // ---- causal j-blocks of 32 (two 16-col score tiles per block) ----
        f32x4 zp = {0.f, 0.f, 0.f, 0.f};
        const int nJb = (T + 2) >> 1;
        for (int Jb = 0; Jb < nJb; ++Jb) {
            const int Jlo = 2 * Jb, Jhi = 2 * Jb + 1;
            const bool hasHi = (Jhi <= T);

            f32x4 slo = {0.f, 0.f, 0.f, 0.f};
            f32x4 shi = {0.f, 0.f, 0.f, 0.f};
            #pragma unroll
            for (int ks = 0; ks < 2; ++ks) {
                us8 bh = *(const us8*)(KhS + KIDX(Jlo * 16 + lr, ks * 32 + lg * 8));
                us8 bl = *(const us8*)(KlS + KIDX(Jlo * 16 + lr, ks * 32 + lg * 8));
                slo = MFMA16(qh[ks], bh, slo);
                slo = MFMA16(qh[ks], bl, slo);
                slo = MFMA16(ql[ks], bh, slo);
            }
            if (hasHi) {
                #pragma unroll
                for (int ks = 0; ks < 2; ++ks) {
                    us8 bh = *(const us8*)(KhS + KIDX(Jhi * 16 + lr, ks * 32 + lg * 8));
                    us8 bl = *(const us8*)(KlS + KIDX(Jhi * 16 + lr, ks * 32 + lg * 8));
                    shi = MFMA16(qh[ks], bh, shi);
                    shi = MFMA16(qh[ks], bl, shi);
                    shi = MFMA16(ql[ks], bh, shi);
                }
            }
            // causal mask on the diagonal tile (C layout: row = lg*4+r, col = lr)
            if (Jlo == T) {
                #pragma unroll
                for (int r = 0; r < 4; ++r)
                    if (lr > lg * 4 + r) slo[r] = 0.f;
            }
            if (hasHi && Jhi == T) {
                #pragma unroll
                for (int r = 0; r < 4; ++r)
                    if (lr > lg * 4 + r) shi[r] = 0.f;
            }
            zp += slo;
            zp += shi;

            // ---- S -> bf16 hi/lo scratch (per-wave, dbuf on Jb parity) ----
            unsigned short* sh = SshS + (w * 2 + (Jb & 1)) * 512;
            unsigned short* sl = SslS + (w * 2 + (Jb & 1)) * 512;
            #pragma unroll
            for (int r = 0; r < 4; ++r) {
                const int row = lg * 4 + r;
                const unsigned short h0 = f2bf(slo[r]);
                sh[SIDX(row, lr)] = h0;
                sl[SIDX(row, lr)] = f2bf(slo[r] - bf2f(h0));
                const unsigned short h1 = f2bf(shi[r]);
                sh[SIDX(row, 16 + lr)] = h1;
                sl[SIDX(row, 16 + lr)] = f2bf(shi[r] - bf2f(h1));
            }
            // wave-internal cross-lane LDS visibility
            asm volatile("s_waitcnt lgkmcnt(0)" ::: "memory");
            __builtin_amdgcn_sched_barrier(0);

            // ---- intra: accO += S . V over this 32-wide j-block ----
            us8 ah = *(const us8*)(sh + SIDX(lr, lg * 8));
            us8 al = *(const us8*)(sl + SIDX(lr, lg * 8));
            #pragma unroll
            for (int mt = 0; mt < 4; ++mt) {
                us8 vh = *(const us8*)(VthS + VTIDX(mt * 16 + lr, Jb * 32 + lg * 8));
                us8 vl = *(const us8*)(VtlS + VTIDX(mt * 16 + lr, Jb * 32 + lg * 8));
                accO[mt] = MFMA16(ah, vh, accO[mt]);
                accO[mt] = MFMA16(ah, vl, accO[mt]);
                accO[mt] = MFMA16(al, vh, accO[mt]);
            }
        }

        // ---- z = eps + u + rowsum(masked S): butterfly over the 16 columns ----
        #pragma unroll
        for (int r = 0; r < 4; ++r) {
            float s = zp[r];
            s += __shfl_xor(s, 1, 64);
            s += __shfl_xor(s, 2, 64);
            s += __shfl_xor(s, 4, 64);
            s += __shfl_xor(s, 8, 64);
            zp[r] = s;
        }

        const size_t ob = ((size_t)(n * Ll + g * Cc + T * 16) * Hh + h) * Mm;
        #pragma unroll
        for (int r = 0; r < 4; ++r) {
            const int row = lg * 4 + r;
            const float ur = __shfl(u, row, 64);
            const float iz = 1.0f / (EPS_ + ur + zp[r]);
            #pragma unroll
            for (int mt = 0; mt < 4; ++mt)
                out[ob + (size_t)row * ROWS + mt * 16 + lr] = accO[mt][r] * iz;
        }
    }
}

extern "C" void kernel_launch(void* const* d_in, const int* in_sizes, int n_in,
                              void* d_out, int out_size, void* d_ws, size_t ws_size,
                              hipStream_t stream) {
    const float* q = (const float*)d_in[0];
    const float* k = (const float*)d_in[1];
    const float* v = (const float*)d_in[2];
    float* out = (float*)d_out;

    // workspace: kvT chunk states (33.5 MB) + ksum chunk states (0.5 MB)
    float* kvbuf   = (float*)d_ws;
    float* ksumbuf = kvbuf + (size_t)Nn * Gg * Hh * Dd * Mm;

    kv_state_kernel<<<Nn * Gg * Hh, 256, 0, stream>>>(k, v, kvbuf, ksumbuf);

    const int nseries = Nn * Hh * Dd * Mm + Nn * Hh * Dd;  // 266240
    prefix_kernel<<<nseries / 256, 256, 0, stream>>>(kvbuf, ksumbuf);

    out_kernel<<<Nn * Gg * Hh, 256, 0, stream>>>(q, k, v, kvbuf, ksumbuf, out);
}

// Round 3
// 285.752 us; speedup vs baseline: 1.8689x; 1.1066x over previous
//
#include <hip/hip_runtime.h>
#include <math.h>

// Causal linear attention, chunkwise. Shapes fixed by the reference:
// [N=4, L=4096, H=16, D=64], M=64, CHUNK=128, G=32.
static constexpr int Nn = 4, Ll = 4096, Hh = 16, Dd = 64, Mm = 64, Cc = 128, Gg = 32;
static constexpr int ROWS = Hh * Dd;  // 1024 floats: l-stride in [N,L,H,D]
#define EPS_ 1e-6f

typedef __bf16 bf16x8 __attribute__((ext_vector_type(8)));
typedef unsigned short us8 __attribute__((ext_vector_type(8)));
typedef float f32x4 __attribute__((ext_vector_type(4)));

__device__ __forceinline__ float phi(float x) {
    // elu(x)+1 = x+1 (x>0) else exp(x)
    return x > 0.0f ? x + 1.0f : __expf(x);
}

// bf16 round-to-nearest-even via bit trick
__device__ __forceinline__ unsigned short f2bf(float x) {
    unsigned u = __float_as_uint(x);
    return (unsigned short)((u + 0x7fffu + ((u >> 16) & 1u)) >> 16);
}
__device__ __forceinline__ float bf2f(unsigned short h) {
    return __uint_as_float(((unsigned)h) << 16);
}

// D = A*B + C, A,B bf16 16x32 / 32x16, C/D f32 16x16.
// A: row = lane&15, k = (lane>>4)*8+e ; B: col = lane&15, k = (lane>>4)*8+e
// C/D: col = lane&15, row = (lane>>4)*4 + reg   (HW-verified layout)
#define MFMA16(A, B, C)                                                      \
    __builtin_amdgcn_mfma_f32_16x16x32_bf16(__builtin_bit_cast(bf16x8, (A)), \
                                            __builtin_bit_cast(bf16x8, (B)), \
                                            (C), 0, 0, 0)

// 16B-granule XOR swizzles. The (m>>4) term spreads the transpose-staging
// b32 writes across all 32 banks (was 8-way conflicted); it is constant per
// fragment-read instruction, so read conflict behavior is unchanged.
__device__ __forceinline__ int KIDX(int j, int d) {   // K [128 j][64 d]
    return j * 64 + ((((d >> 3) ^ j) & 7) << 3) + (d & 7);
}
__device__ __forceinline__ int VTIDX(int m, int j) {  // T-layout [64 rows][128 cols]
    return m * 128 + ((((j >> 3) ^ (m & 15) ^ (m >> 4)) & 15) << 3) + (j & 7);
}

__device__ __forceinline__ void load8(const float* p, float* xs) {
    float4 a = *(const float4*)p, b = *(const float4*)(p + 4);
    xs[0] = a.x; xs[1] = a.y; xs[2] = a.z; xs[3] = a.w;
    xs[4] = b.x; xs[5] = b.y; xs[6] = b.z; xs[7] = b.w;
}

// unpack 8 packed (hi|lo<<16) u32 -> hi us8, lo us8 via v_perm_b32
__device__ __forceinline__ void unpack8(const unsigned* p, us8& hi, us8& lo) {
    const uint4 a = *(const uint4*)p;
    const uint4 b = *(const uint4*)(p + 4);
    union { unsigned u[4]; us8 v; } H, L;
    H.u[0] = __builtin_amdgcn_perm(a.y, a.x, 0x05040100u);
    L.u[0] = __builtin_amdgcn_perm(a.y, a.x, 0x07060302u);
    H.u[1] = __builtin_amdgcn_perm(a.w, a.z, 0x05040100u);
    L.u[1] = __builtin_amdgcn_perm(a.w, a.z, 0x07060302u);
    H.u[2] = __builtin_amdgcn_perm(b.y, b.x, 0x05040100u);
    L.u[2] = __builtin_amdgcn_perm(b.y, b.x, 0x07060302u);
    H.u[3] = __builtin_amdgcn_perm(b.w, b.z, 0x05040100u);
    L.u[3] = __builtin_amdgcn_perm(b.w, b.z, 0x07060302u);
    hi = H.v; lo = L.v;
}

// ---------------------------------------------------------------------------
// Kernel 1: per-chunk TRANSPOSED KV state via MFMA.
//   kvT[m][d] = sum_c v[c][m] * phi(k[c][d])   (= (V^T . phi(K)) [m][d])
//   ksum[d]   = sum_c phi(k[c][d])
// One block per (n,g,h), 4 waves; wave w owns m-tile [w*16, w*16+16).
// ---------------------------------------------------------------------------
__global__ __launch_bounds__(256, 2) void kv_state_kernel(
    const float* __restrict__ keys, const float* __restrict__ values,
    float* __restrict__ kvbuf, float* __restrict__ ksumbuf)
{
    __shared__ alignas(16) unsigned short KthS[64 * 128];  // kT [d][c] hi
    __shared__ alignas(16) unsigned short KtlS[64 * 128];  // kT [d][c] lo
    __shared__ alignas(16) unsigned short VthS[64 * 128];  // vT [m][c] hi
    __shared__ alignas(16) unsigned short VtlS[64 * 128];  // vT [m][c] lo

    const int b = blockIdx.x;
    const int h = b % Hh;
    const int g = (b / Hh) % Gg;
    const int n = b / (Hh * Gg);
    const int tid = threadIdx.x;

    const size_t inbase = ((size_t)(n * Ll + g * Cc) * Hh + h) * Dd;

    // stage both transposes: row-pairs -> packed u32 (hi|hi<<16) writes
    for (int i = tid; i < 1024; i += 256) {
        const int jp = i >> 4, d4 = (i & 15) * 4;
        const int c0 = jp * 2;
        const float4 ka = *(const float4*)(keys   + inbase + (size_t)c0 * ROWS + d4);
        const float4 kb = *(const float4*)(keys   + inbase + (size_t)(c0 + 1) * ROWS + d4);
        const float4 va = *(const float4*)(values + inbase + (size_t)c0 * ROWS + d4);
        const float4 vb = *(const float4*)(values + inbase + (size_t)(c0 + 1) * ROWS + d4);
        const float kaa[4] = {ka.x, ka.y, ka.z, ka.w};
        const float kbb[4] = {kb.x, kb.y, kb.z, kb.w};
        const float vaa[4] = {va.x, va.y, va.z, va.w};
        const float vbb[4] = {vb.x, vb.y, vb.z, vb.w};
        #pragma unroll
        for (int e = 0; e < 4; ++e) {
            const int idx = VTIDX(d4 + e, c0);  // c0 even -> u32-aligned, same granule
            const float pa = phi(kaa[e]), pb = phi(kbb[e]);
            const unsigned ha = f2bf(pa), hb = f2bf(pb);
            *(unsigned*)(KthS + idx) = ha | (hb << 16);
            const unsigned la = f2bf(pa - bf2f((unsigned short)ha));
            const unsigned lb = f2bf(pb - bf2f((unsigned short)hb));
            *(unsigned*)(KtlS + idx) = la | (lb << 16);
            const unsigned hva = f2bf(vaa[e]), hvb = f2bf(vbb[e]);
            *(unsigned*)(VthS + idx) = hva | (hvb << 16);
            const unsigned lva = f2bf(vaa[e] - bf2f((unsigned short)hva));
            const unsigned lvb = f2bf(vbb[e] - bf2f((unsigned short)hvb));
            *(unsigned*)(VtlS + idx) = lva | (lvb << 16);
        }
    }
    __syncthreads();

    const int w = tid >> 6, l = tid & 63;
    const int lr = l & 15, lg = l >> 4;

    // A = vT fragments for this wave's m-tile
    us8 ah[4], al[4];
    #pragma unroll
    for (int cs = 0; cs < 4; ++cs) {
        ah[cs] = *(const us8*)(VthS + VTIDX(w * 16 + lr, cs * 32 + lg * 8));
        al[cs] = *(const us8*)(VtlS + VTIDX(w * 16 + lr, cs * 32 + lg * 8));
    }

    float* kvout = kvbuf + ((size_t)((n * Gg + g) * Hh + h)) * (Dd * Mm);
    __builtin_amdgcn_s_setprio(1);
    #pragma unroll
    for (int dt = 0; dt < 4; ++dt) {
        f32x4 acc = {0.f, 0.f, 0.f, 0.f};
        #pragma unroll
        for (int cs = 0; cs < 4; ++cs) {
            us8 bh = *(const us8*)(KthS + VTIDX(dt * 16 + lr, cs * 32 + lg * 8));
            us8 bl = *(const us8*)(KtlS + VTIDX(dt * 16 + lr, cs * 32 + lg * 8));
            acc = MFMA16(ah[cs], bh, acc);
            acc = MFMA16(ah[cs], bl, acc);
            acc = MFMA16(al[cs], bh, acc);
        }
        // C layout: row (m within tile) = lg*4+r, col (d within tile) = lr
        #pragma unroll
        for (int r = 0; r < 4; ++r)
            kvout[(size_t)(w * 16 + lg * 4 + r) * 64 + dt * 16 + lr] = acc[r];
    }
    __builtin_amdgcn_s_setprio(0);

    if (tid < 64) {
        float s = 0.f;
        #pragma unroll
        for (int gb = 0; gb < 16; ++gb) {
            us8 hh = *(const us8*)(KthS + VTIDX(tid, gb * 8));
            us8 ll = *(const us8*)(KtlS + VTIDX(tid, gb * 8));
            #pragma unroll
            for (int e = 0; e < 8; ++e) s += bf2f(hh[e]) + bf2f(ll[e]);
        }
        ksumbuf[((size_t)((n * Gg + g) * Hh + h)) * 64 + tid] = s;
    }
}

// ---------------------------------------------------------------------------
// Kernel 2: in-place EXCLUSIVE prefix over g.
// kvbuf: fp32 accumulate, but each output element is written back PACKED as
// bf16 (hi | lo<<16) into the same u32 slot -> out_kernel reads B-fragments
// directly from global (no LDS staging). ksum stays fp32.
// ---------------------------------------------------------------------------
__global__ __launch_bounds__(256) void prefix_kernel(
    float* __restrict__ kvbuf, float* __restrict__ ksumbuf)
{
    const int t = blockIdx.x * 256 + threadIdx.x;
    const int NKV = Nn * Hh * Dd * Mm;  // 262144
    if (t < NKV) {
        const int nh = t >> 12, dm = t & 4095;
        const int n = nh >> 4, h = nh & 15;
        unsigned* kvp = (unsigned*)kvbuf;
        float run = 0.f;
        for (int g = 0; g < Gg; ++g) {
            const size_t idx = ((size_t)((n * Gg + g) * Hh + h)) * 4096 + dm;
            const float v = kvbuf[idx];
            const unsigned hb = f2bf(run);
            const unsigned lb = f2bf(run - bf2f((unsigned short)hb));
            kvp[idx] = hb | (lb << 16);
            run += v;
        }
    } else {
        const int t2 = t - NKV;
        if (t2 < Nn * Hh * Dd) {
            const int nh = t2 >> 6, d = t2 & 63;
            const int n = nh >> 4, h = nh & 15;
            float run = 0.f;
            for (int g = 0; g < Gg; ++g) {
                const size_t idx = ((size_t)((n * Gg + g) * Hh + h)) * 64 + d;
                const float v = ksumbuf[idx];
                ksumbuf[idx] = run;
                run += v;
            }
        }
    }
}

// ---------------------------------------------------------------------------
// Kernel 3: MFMA out kernel. One block per (n,g,h) chunk, 4 waves.
// Wave w owns 16-row tiles T = w and 7-w (balanced causal triangle).
// LDS ~74 KB -> 2 blocks/CU (2 waves/SIMD, cross-block phase overlap).
// KVprev B-fragments come straight from global (packed bf16 hi/lo planes).
// ---------------------------------------------------------------------------
__global__ __launch_bounds__(256, 2) void out_kernel(
    const float* __restrict__ queries,
    const float* __restrict__ keys,
    const float* __restrict__ values,
    const float* __restrict__ kvbuf,
    const float* __restrict__ ksumbuf,
    float* __restrict__ out)
{
    __shared__ alignas(16) unsigned short KhS[128 * 64];   // 16 KB phi(k) hi
    __shared__ alignas(16) unsigned short KlS[128 * 64];   // 16 KB phi(k) lo
    __shared__ alignas(16) unsigned short VthS[64 * 128];  // 16 KB V^T hi
    __shared__ alignas(16) unsigned short VtlS[64 * 128];  // 16 KB V^T lo
    __shared__ alignas(16) unsigned short SshS[4 * 512];   //  4 KB per-wave S hi
    __shared__ alignas(16) unsigned short SslS[4 * 512];   //  4 KB per-wave S lo
    __shared__ float kpreS[64];

    const int b = blockIdx.x;
    const int h = b & 15, g = (b >> 4) & 31, n = b >> 9;
    const int tid = threadIdx.x;

    const size_t chunkbase = ((size_t)(n * Ll + g * Cc) * Hh + h) * Dd;
    const size_t stateoff  = (size_t)((n * Gg + g) * Hh + h);

    // ---- stage kpre (exclusive prefix of column-sums of phi(k)) ----
    if (tid < 16)
        *(float4*)(kpreS + tid * 4) =
            *(const float4*)(ksumbuf + stateoff * 64 + tid * 4);

    // ---- stage phi(k) hi/lo, granule-swizzled (contiguous us8 writes) ----
    for (int t = tid; t < 1024; t += 256) {
        const int j = t >> 3, gb = t & 7;
        float xs[8];
        load8(keys + chunkbase + (size_t)j * ROWS + gb * 8, xs);
        us8 hh, ll;
        #pragma unroll
        for (int e = 0; e < 8; ++e) {
            const float p = phi(xs[e]);
            const unsigned short hb = f2bf(p);
            hh[e] = hb; ll[e] = f2bf(p - bf2f(hb));
        }
        const int base = KIDX(j, gb * 8);
        *(us8*)(KhS + base) = hh;
        *(us8*)(KlS + base) = ll;
    }
    // ---- stage V transposed hi/lo (row pairs -> packed b32 writes) ----
    for (int t = tid; t < 1024; t += 256) {
        const int jp = t >> 4, m4 = (t & 15) * 4;
        const int j0 = jp * 2;
        const float4 va = *(const float4*)(values + chunkbase + (size_t)j0 * ROWS + m4);
        const float4 vb = *(const float4*)(values + chunkbase + (size_t)(j0 + 1) * ROWS + m4);
        const float vaa[4] = {va.x, va.y, va.z, va.w};
        const float vbb[4] = {vb.x, vb.y, vb.z, vb.w};
        #pragma unroll
        for (int e = 0; e < 4; ++e) {
            const int idx = VTIDX(m4 + e, j0);  // j0 even -> aligned, same granule
            const unsigned hva = f2bf(vaa[e]), hvb = f2bf(vbb[e]);
            *(unsigned*)(VthS + idx) = hva | (hvb << 16);
            const unsigned lva = f2bf(vaa[e] - bf2f((unsigned short)hva));
            const unsigned lvb = f2bf(vbb[e] - bf2f((unsigned short)hvb));
            *(unsigned*)(VtlS + idx) = lva | (lvb << 16);
        }
    }
    __syncthreads();

    const int w = tid >> 6, l = tid & 63;
    const int lr = l & 15, lg = l >> 4;
    const unsigned* kvpk = (const unsigned*)kvbuf + stateoff * (size_t)4096;

    for (int tt = 0; tt < 2; ++tt) {
        const int T = tt ? (7 - w) : w;  // balanced pairing: {w, 7-w}

        // ---- Q fragments straight from global (phi + split) and u = Q.kpre ----
        us8 qh[2], ql[2];
        float u = 0.f;
        #pragma unroll
        for (int ks = 0; ks < 2; ++ks) {
            float xs[8];
            load8(queries + chunkbase + (size_t)(T * 16 + lr) * ROWS + ks * 32 + lg * 8, xs);
            us8 hh, ll;
            #pragma unroll
            for (int e = 0; e < 8; ++e) {
                const float p = phi(xs[e]);
                u += p * kpreS[ks * 32 + lg * 8 + e];
                const unsigned short hb = f2bf(p);
                hh[e] = hb; ll[e] = f2bf(p - bf2f(hb));
            }
            qh[ks] = hh; ql[ks] = ll;
        }
        // reduce u over the 4 d-groups; afterwards lane i<16 holds u for row T*16+i
        u += __shfl_xor(u, 16, 64);
        u += __shfl_xor(u, 32, 64);

        // ---- inter: accO = Q . KVprev (B-frags from global packed planes) ----
        f32x4 accO[4];
        #pragma unroll
        for (int mt = 0; mt < 4; ++mt) {
            const unsigned* p = kvpk + (size_t)(mt * 16 + lr) * 64 + lg * 8;
            us8 bh0, bl0, bh1, bl1;
            unpack8(p, bh0, bl0);
            unpack8(p + 32, bh1, bl1);
            f32x4 acc = {0.f, 0.f, 0.f, 0.f};
            acc = MFMA16(qh[0], bh0, acc);
            acc = MFMA16(qh[0], bl0, acc);
            acc = MFMA16(ql[0], bh0, acc);
            acc = MFMA16(qh[1], bh1, acc);
            acc = MFMA16(qh[1], bl1, acc);
            acc = MFMA16(ql[1], bh1, acc);
            accO[mt] = acc;
        }

        // ---- causal j-blocks of 32 (two 16-col score tiles per block) ----
        f32x4 zp = {0.f, 0.f, 0.f, 0.f};
        const int nJb = (T + 2) >> 1;
        for (int Jb = 0; Jb < nJb; ++Jb) {
            const int Jlo = 2 * Jb, Jhi = 2 * Jb + 1;
            const bool hasHi = (Jhi <= T);

            f32x4 slo = {0.f, 0.f, 0.f, 0.f};
            f32x4 shi = {0.f, 0.f, 0.f, 0.f};
            __builtin_amdgcn_s_setprio(1);
            #pragma unroll
            for (int ks = 0; ks < 2; ++ks) {
                us8 bh = *(const us8*)(KhS + KIDX(Jlo * 16 + lr, ks * 32 + lg * 8));
                us8 bl = *(const us8*)(KlS + KIDX(Jlo * 16 + lr, ks * 32 + lg * 8));
                slo = MFMA16(qh[ks], bh, slo);
                slo = MFMA16(qh[ks], bl, slo);
                slo = MFMA16(ql[ks], bh, slo);
            }
            if (hasHi) {
                #pragma unroll
                for (int ks = 0; ks < 2; ++ks) {
                    us8 bh = *(const us8*)(KhS + KIDX(Jhi * 16 + lr, ks * 32 + lg * 8));
                    us8 bl = *(const us8*)(KlS + KIDX(Jhi * 16 + lr, ks * 32 + lg * 8));
                    shi = MFMA16(qh[ks], bh, shi);
                    shi = MFMA16(qh[ks], bl, shi);
                    shi = MFMA16(ql[ks], bh, shi);
                }
            }
            __builtin_amdgcn_s_setprio(0);
            // causal mask on the diagonal tile (C layout: row = lg*4+r, col = lr)
            if (Jlo == T) {
                #pragma unroll
                for (int r = 0; r < 4; ++r)
                    if (lr > lg * 4 + r) slo[r] = 0.f;
            }
            if (hasHi && Jhi == T) {
                #pragma unroll
                for (int r = 0; r < 4; ++r)
                    if (lr > lg * 4 + r) shi[r] = 0.f;
            }
            zp += slo;
            zp += shi;

            // ---- S -> bf16 hi/lo scratch (per-wave, single-buffered:
            //      DS ops are in-order per wave, so WAR within the wave is safe)
            unsigned short* sh = SshS + w * 512;
            unsigned short* sl = SslS + w * 512;
            #pragma unroll
            for (int r = 0; r < 4; ++r) {
                const int row = lg * 4 + r;
                const unsigned short h0 = f2bf(slo[r]);
                sh[row * 32 + lr]      = h0;
                sl[row * 32 + lr]      = f2bf(slo[r] - bf2f(h0));
                const unsigned short h1 = f2bf(shi[r]);
                sh[row * 32 + 16 + lr] = h1;
                sl[row * 32 + 16 + lr] = f2bf(shi[r] - bf2f(h1));
            }
            // wave-internal cross-lane LDS visibility
            asm volatile("s_waitcnt lgkmcnt(0)" ::: "memory");
            __builtin_amdgcn_sched_barrier(0);

            // ---- intra: accO += S . V over this 32-wide j-block ----
            us8 ah = *(const us8*)(sh + lr * 32 + lg * 8);
            us8 al = *(const us8*)(sl + lr * 32 + lg * 8);
            __builtin_amdgcn_s_setprio(1);
            #pragma unroll
            for (int mt = 0; mt < 4; ++mt) {
                us8 vh = *(const us8*)(VthS + VTIDX(mt * 16 + lr, Jb * 32 + lg * 8));
                us8 vl = *(const us8*)(VtlS + VTIDX(mt * 16 + lr, Jb * 32 + lg * 8));
                accO[mt] = MFMA16(ah, vh, accO[mt]);
                accO[mt] = MFMA16(ah, vl, accO[mt]);
                accO[mt] = MFMA16(al, vh, accO[mt]);
            }
            __builtin_amdgcn_s_setprio(0);
        }

        // ---- z = eps + u + rowsum(masked S): butterfly over the 16 columns ----
        #pragma unroll
        for (int r = 0; r < 4; ++r) {
            float s = zp[r];
            s += __shfl_xor(s, 1, 64);
            s += __shfl_xor(s, 2, 64);
            s += __shfl_xor(s, 4, 64);
            s += __shfl_xor(s, 8, 64);
            zp[r] = s;
        }

        const size_t ob = ((size_t)(n * Ll + g * Cc + T * 16) * Hh + h) * Mm;
        #pragma unroll
        for (int r = 0; r < 4; ++r) {
            const int row = lg * 4 + r;
            const float ur = __shfl(u, row, 64);
            const float iz = 1.0f / (EPS_ + ur + zp[r]);
            #pragma unroll
            for (int mt = 0; mt < 4; ++mt)
                out[ob + (size_t)row * ROWS + mt * 16 + lr] = accO[mt][r] * iz;
        }
    }
}

extern "C" void kernel_launch(void* const* d_in, const int* in_sizes, int n_in,
                              void* d_out, int out_size, void* d_ws, size_t ws_size,
                              hipStream_t stream) {
    const float* q = (const float*)d_in[0];
    const float* k = (const float*)d_in[1];
    const float* v = (const float*)d_in[2];
    float* out = (float*)d_out;

    // workspace: kvT chunk states (33.5 MB, fp32 then packed-in-place by
    // prefix) + ksum chunk states (0.5 MB)
    float* kvbuf   = (float*)d_ws;
    float* ksumbuf = kvbuf + (size_t)Nn * Gg * Hh * Dd * Mm;

    kv_state_kernel<<<Nn * Gg * Hh, 256, 0, stream>>>(k, v, kvbuf, ksumbuf);

    const int nseries = Nn * Hh * Dd * Mm + Nn * Hh * Dd;  // 266240
    prefix_kernel<<<nseries / 256, 256, 0, stream>>>(kvbuf, ksumbuf);

    out_kernel<<<Nn * Gg * Hh, 256, 0, stream>>>(q, k, v, kvbuf, ksumbuf, out);
}